// Round 14
// baseline (126.317 us; speedup 1.0000x reference)
//
#include <hip/hip_runtime.h>

// ---------------------------------------------------------------------------
// SgpiSTFT: Hermitian iFFT (as GEMM vs fixed cos/sin matrix) + window + 4-tap
// overlap-add + flip/transpose, fused.
//
//   y[n,t] = Re(c0) + 2*sum_{k=1..255}( Re_k cos(2pi n k/512) + Im_k sin(...) )
//   out[b, t*256 + (255-j)] = 256*( y[256+j,t]  *win[768+j]
//                                  + y[j,  t-1] *win[512+j]
//                                  + y[256+j,t-2]*win[256+j]
//                                  + y[j,  t-3] *win[j] )
// E/O split: Y=E+O (y[j]), Yh=E-O (y[256+j]).
//
// Round-14: FAT WAVES (4 j-tiles/wave). Eight structural nulls (R0..R13) at
// 42-49us isolated the limiter: every wave re-reads the whole 64KB X tile for
// only 16-32 output cols -> 16x LDS amplification (1024 ds_read_b128/block @
// ~17.5cyc incl. conflicts) with MFMA:read = 8:4. R13 proved K-loop cost
// scales with per-wave serial work, not wave count. This round: 256 thr /
// 4 waves, wave w owns j-tiles {4w..4w+3}; per step 4 A-reads feed 16 MFMAs
// (ratio 16:4); block LDS reads 1024->256. acc=128 VGPR, launch_bounds(256,1)
// (512-reg budget, no R6-style spill). LDS 64KiB -> 2 blocks/CU; grid 536 ~
// 1.05 resident rounds. M layout / X layout+swizzle / fragment formula /
// epilogue math preserved bit-for-bit from the validated R5 kernel.
// ---------------------------------------------------------------------------

typedef __attribute__((ext_vector_type(8))) short short8;
typedef __attribute__((ext_vector_type(8))) __bf16 bf16x8;
typedef __attribute__((ext_vector_type(4))) float floatx4;

__device__ inline short f2bf(float f) {
  unsigned u = __builtin_bit_cast(unsigned, f);
  u = (u + 0x7fffu + ((u >> 16) & 1u)) >> 16;
  return (short)(unsigned short)u;
}

#define PI_OVER_256 0.01227184630308513f

// M matrix in MFMA fragment order (validated R3/R5/R9):
//   frag idx = (Jtile*16 + s)*64 + lane ; lane holds row j = Jtile*16+(lane&15),
//   kappa = s*32 + (lane>>4)*8 + e, e=0..7 (one short8 per lane).
//   kappa < 256: gk = 2*kappa (even);  kappa >= 256: gk = 2*(kappa-256)+1 (odd)
//   M[j][gk] = (gk==0) ? 1 : (gk<256 ? 2cos(2pi j gk/512) : 2sin(2pi j (gk-256)/512))
__global__ void build_m(short* __restrict__ M) {
  int idx = blockIdx.x * blockDim.x + threadIdx.x;  // [0, 16*16*64)
  int ntile = idx >> 10;
  int s = (idx >> 6) & 15;
  int lane = idx & 63;
  int n = ntile * 16 + (lane & 15);
  int kb = lane >> 4;
  short8 v;
#pragma unroll
  for (int e = 0; e < 8; e++) {
    int kap = s * 32 + kb * 8 + e;
    int gk = 2 * (kap & 255) + (kap >> 8);
    float val;
    if (gk == 0) {
      val = 1.0f;
    } else if (gk < 256) {
      int m = (n * gk) & 511;
      val = 2.0f * __cosf((float)m * PI_OVER_256);
    } else {
      int m = (n * (gk - 256)) & 511;
      val = 2.0f * __sinf((float)m * PI_OVER_256);
    }
    v[e] = f2bf(val);
  }
  ((short8*)M)[idx] = v;
}

// Block: batch b, X columns [c0, c0+64), c0 = 60*tile - 4 (halo 4). Outputs
// local L in [4,64) -> t = c0+L, masked to t <= 3998. 256 threads = 4 waves;
// wave w owns j-tiles {4w..4w+3} (j rows 64w..64w+63) for all 64 t-columns.
__global__ __launch_bounds__(256, 1) void gemm_ola(
    const float* __restrict__ in, const float* __restrict__ win,
    const short* __restrict__ M, float* __restrict__ out) {
  // X tile, bf16, column-major [col][kappa], kappa groups of 8 XOR-swizzled
  // by (col&7) -> conflict-light b128 reads (same layout as R5, validated).
  __shared__ short ldsX[64 * 512];  // 64 KiB

  const int tid = threadIdx.x;
  const int b = blockIdx.y;
  const int tile = blockIdx.x;
  const int c0 = 60 * tile - 4;

  // ---- stage X: 4 batches of {8 dwordx4 loads -> cvt -> 4 b128 writes} ----
  // thread covers 4 cols (cbase) x 32 kappa (kbase..kbase+31).
  {
    const int cbase = 4 * (tid & 15);   // 16 col-groups
    const int kbase = (tid >> 4) * 32;  // 16 kappa-threads x 32 kappa
    const int gc = c0 + cbase;
    const bool ok = (gc >= 0 && gc <= 3996);
    const float* src = in + (size_t)b * 2056000 + gc;
#pragma unroll
    for (int bt = 0; bt < 4; bt++) {
      const int kap0 = kbase + 8 * bt;
      floatx4 f[8];
      if (ok) {
#pragma unroll
        for (int j = 0; j < 8; j++) {
          int kap = kap0 + j;
          int gk = 2 * (kap & 255) + (kap >> 8);
          int row = (gk < 256) ? gk : gk + 1;  // imag rows start at 257
          f[j] = *(const floatx4*)(src + (size_t)row * 4000);
        }
      } else {
#pragma unroll
        for (int j = 0; j < 8; j++) f[j] = floatx4{0.f, 0.f, 0.f, 0.f};
      }
      const int g = kap0 >> 3;  // 8-aligned kappa-group
#pragma unroll
      for (int cc = 0; cc < 4; cc++) {
        short8 v;
#pragma unroll
        for (int j = 0; j < 8; j++) v[j] = f2bf(f[j][cc]);
        const int col = cbase + cc;
        *(short8*)&ldsX[col * 512 + ((g ^ (col & 7)) << 3)] = v;
      }
    }
  }
  __syncthreads();

  const int w = tid >> 6;    // wave id 0..3; owns j-tiles 4w..4w+3
  const int lane = tid & 63;
  const int c = lane & 15;   // MFMA spatial index within 16-tile
  const int rg = lane >> 4;  // k-block; also C row-group

  // acc[q][jt]: q = t-tile (4 x 16 cols), jt = j-tile offset (0..3)
  floatx4 accE[4][4] = {};
  floatx4 accO[4][4] = {};

  const short8* Mf = (const short8*)M;

  bf16x8 cb[4];
#pragma unroll
  for (int jt = 0; jt < 4; jt++)
    cb[jt] = __builtin_bit_cast(bf16x8, Mf[((4 * w + jt) * 16 + 0) * 64 + lane]);

#pragma unroll
  for (int s = 0; s < 16; s++) {
    // prefetch next-s M fragments (L2) before this step's MFMAs
    bf16x8 nb[4];
    if (s < 15) {
#pragma unroll
      for (int jt = 0; jt < 4; jt++)
        nb[jt] = __builtin_bit_cast(
            bf16x8, Mf[((4 * w + jt) * 16 + s + 1) * 64 + lane]);
    }
    // A fragments (X) from LDS: lane m = t-col; (16q+c)&7 == c&7.
    const int g = 4 * s + rg;
    bf16x8 a[4];
#pragma unroll
    for (int q = 0; q < 4; q++) {
      const int col = 16 * q + c;
      a[q] = __builtin_bit_cast(
          bf16x8, *(const short8*)&ldsX[col * 512 + ((g ^ (c & 7)) << 3)]);
    }
    // 16 independent MFMAs per step (4 A-reads amortized over 4 B-frags)
    if (s < 8) {
#pragma unroll
      for (int q = 0; q < 4; q++)
#pragma unroll
        for (int jt = 0; jt < 4; jt++)
          accE[q][jt] = __builtin_amdgcn_mfma_f32_16x16x32_bf16(
              a[q], cb[jt], accE[q][jt], 0, 0, 0);
    } else {
#pragma unroll
      for (int q = 0; q < 4; q++)
#pragma unroll
        for (int jt = 0; jt < 4; jt++)
          accO[q][jt] = __builtin_amdgcn_mfma_f32_16x16x32_bf16(
              a[q], cb[jt], accO[q][jt], 0, 0, 0);
    }
    if (s < 15) {
#pragma unroll
      for (int jt = 0; jt < 4; jt++) cb[jt] = nb[jt];
    }
  }

  // ---- OLA epilogue (validated R5 math, run per jt) ----
  // C layout: col (lane&15) = j within j-tile; row (rg*4+p) = local t offset.
  // Tap t-d = reg p-d; p-d<0 pulls reg p-d+4 from the row-group below
  // (lane-16, same q-tile) or, for rg==0, from rg=3 of tile q-1 (lane+48).
  // q==0 && rg==0 edge rows are L<4 -> masked.
#pragma unroll
  for (int jt = 0; jt < 4; jt++) {
    const int j = 16 * (4 * w + jt) + c;
    const float wv0 = 256.0f * win[768 + j];
    const float wv1 = 256.0f * win[512 + j];
    const float wv2 = 256.0f * win[256 + j];
    const float wv3 = 256.0f * win[j];

    floatx4 Y[4], Yh[4];
#pragma unroll
    for (int q = 0; q < 4; q++) {
      Y[q] = accE[q][jt] + accO[q][jt];
      Yh[q] = accE[q][jt] - accO[q][jt];
    }

#pragma unroll
    for (int q = 0; q < 4; q++) {
      const int qm = (q > 0) ? q - 1 : 0;  // q==0 edge is masked (L<4)
      float yb[4], yhb[4];
#pragma unroll
      for (int p = 1; p < 4; p++) {
        float ia = __shfl(Y[q][p], lane - 16, 64);
        float pa = __shfl(Y[qm][p], lane + 48, 64);
        yb[p] = (rg > 0) ? ia : pa;
      }
#pragma unroll
      for (int p = 2; p < 4; p++) {
        float ia = __shfl(Yh[q][p], lane - 16, 64);
        float pa = __shfl(Yh[qm][p], lane + 48, 64);
        yhb[p] = (rg > 0) ? ia : pa;
      }
      floatx4 v;
#pragma unroll
      for (int p = 0; p < 4; p++) {
        float t1 = (p >= 1) ? Y[q][p - 1] : yb[3];
        float t2 = (p >= 2) ? Yh[q][p - 2] : yhb[p + 2];
        float t3 = (p >= 3) ? Y[q][p - 3] : yb[p + 1];
        v[p] = wv0 * Yh[q][p] + wv1 * t1 + wv2 * t2 + wv3 * t3;
      }
#pragma unroll
      for (int p = 0; p < 4; p++) {
        const int L = 16 * q + 4 * rg + p;
        const int t = c0 + L;
        if (L >= 4 && t <= 3998) {
          out[((size_t)b * 3999 + t) * 256 + (255 - j)] = v[p];
        }
      }
    }
  }
}

extern "C" void kernel_launch(void* const* d_in, const int* in_sizes, int n_in,
                              void* d_out, int out_size, void* d_ws, size_t ws_size,
                              hipStream_t stream) {
  const float* in = (const float*)d_in[0];   // (8, 514, 4000) fp32
  const float* win = (const float*)d_in[1];  // (1024,) fp32
  float* out = (float*)d_out;                // (8, 3999*256) fp32
  short* M = (short*)d_ws;                   // 256 KiB bf16 coefficient matrix

  hipLaunchKernelGGL(build_m, dim3(64), dim3(256), 0, stream, M);
  hipLaunchKernelGGL(gemm_ola, dim3(67, 8), dim3(256), 0, stream, in, win, M, out);
}